// Round 2
// 484.263 us; speedup vs baseline: 1.0482x; 1.0482x over previous
//
#include <hip/hip_runtime.h>
#include <hip/hip_bf16.h>

#define IN_F   4096
#define OUT_F  4096
#define BK     64
#define NTILES (IN_F / BK)   // 64

typedef __bf16 bf16;
typedef __attribute__((ext_vector_type(8)))  __bf16 bf16x8;
typedef __attribute__((ext_vector_type(4)))  __bf16 bf16x4;
typedef __attribute__((ext_vector_type(4)))  float  floatx4;

// ---------------------------------------------------------------------------
// Merged pre-pass: blocks [0, nxb) convert x fp32->bf16 (8 floats/thread,
// 32B loads + 16B stores); blocks [nxb, ...) unpack+dequant W to bf16 (N,K).
// ---------------------------------------------------------------------------
__global__ __launch_bounds__(256) void prep_kernel(
    const float* __restrict__ x,  bf16* __restrict__ xb,
    const int* __restrict__ Wp,   const float* __restrict__ scale,
    const float* __restrict__ zero, bf16* __restrict__ Wb, int nxb)
{
    if ((int)blockIdx.x < nxb) {
        const size_t i = (size_t)blockIdx.x * 256 + threadIdx.x;
        const float4 v0 = ((const float4*)x)[2 * i];
        const float4 v1 = ((const float4*)x)[2 * i + 1];
        bf16x8 b;
        b[0] = (bf16)v0.x; b[1] = (bf16)v0.y; b[2] = (bf16)v0.z; b[3] = (bf16)v0.w;
        b[4] = (bf16)v1.x; b[5] = (bf16)v1.y; b[6] = (bf16)v1.z; b[7] = (bf16)v1.w;
        ((bf16x8*)xb)[i] = b;
    } else {
        const int tid = (blockIdx.x - nxb) * 256 + threadIdx.x;  // one packed word
        const int n = tid >> 9;                  // / (IN_F/8)
        const int b = tid & 511;
        const int g = (n << 6) + (b >> 3);       // group = n*64 + k/64
        const float sc = scale[g];
        const float zp = zero[g];
        const bf16 hi = (bf16)((1.0f - zp) * sc);
        const bf16 lo = (bf16)((0.0f - zp) * sc);
        const int v = Wp[tid];
        bf16x8 w;
#pragma unroll
        for (int j = 0; j < 8; ++j) w[j] = ((v >> j) & 1) ? hi : lo;
        *(bf16x8*)&Wb[(size_t)tid * 8] = w;
    }
}

// ---------------------------------------------------------------------------
// 256x256x64 8-phase counted-vmcnt GEMM (m201 template, plain HIP).
// out(M,N) = A(M,K)bf16 @ B(N,K)^T + bias, fp32 out.
// 8 waves (2M x 4N), per-wave 128x64 output, 16x16x32 MFMA.
// LDS: 2 K-tile double buffer, [256][64] per matrix, unit ^= (row&7) swizzle
// applied on BOTH sides (pre-swizzled global source for global_load_lds,
// swizzled ds_read address).
// Tail fix (this round): last-2-iteration waits tightened — with s1/s2 false
// fewer loads are outstanding, so vmcnt(6)/vmcnt(4) no longer force the
// final tile's stages; use vmcnt(0)/vmcnt(2) there instead.
// ---------------------------------------------------------------------------
__device__ __forceinline__ void gload_lds16(const void* g, void* l) {
    __builtin_amdgcn_global_load_lds(
        (const __attribute__((address_space(1))) unsigned int*)g,
        (__attribute__((address_space(3))) unsigned int*)l, 16, 0, 0);
}

#define CFENCE asm volatile("" ::: "memory")
#define SBAR() do { CFENCE; __builtin_amdgcn_s_barrier(); CFENCE; } while (0)
#define WAIT_LGKM0 asm volatile("s_waitcnt lgkmcnt(0)" ::: "memory")

// stage one 64-row quarter (q) of a (row0 + 256)x64 K-slab into LDS tile.
// wave w stages rows q*64 + w*8 .. +8; lane l: row += l>>3, stored unit l&7,
// global unit (l&7) ^ (row&7)  => LDS[r][s] = G[r][s ^ (r&7)].
#define STAGE(src, ldsTile, q, row0, kti) do {                                 \
    const int r_  = (q) * 64 + wave * 8 + srow;                                \
    const int gu_ = sun ^ (r_ & 7);                                            \
    gload_lds16((src) + (size_t)((row0) + r_) * IN_F + (kti) * BK + gu_ * 8,   \
                (ldsTile) + ((q) * 64 + wave * 8) * BK);                       \
} while (0)

// read a bf16x8 fragment: logical (row, 16B-unit u) -> stored unit u^(row&7)
#define LDFRAG(tile, row, u) \
    (*(const bf16x8*)((tile) + (row) * BK + (((u) ^ ((row) & 7)) << 3)))

#define LOAD_A(tile, MS)                                                       \
    _Pragma("unroll")                                                          \
    for (int i = 0; i < 4; ++i)                                                \
        _Pragma("unroll")                                                      \
        for (int ks = 0; ks < 2; ++ks)                                         \
            af[i][ks] = LDFRAG((tile), wm * 128 + (MS) * 64 + i * 16 + l15,    \
                               ks * 4 + l4);

#define LOAD_B(tile, NS)                                                       \
    _Pragma("unroll")                                                          \
    for (int j = 0; j < 2; ++j)                                                \
        _Pragma("unroll")                                                      \
        for (int ks = 0; ks < 2; ++ks)                                         \
            bfr[j][ks] = LDFRAG((tile), wn * 64 + (NS) * 32 + j * 16 + l15,    \
                                ks * 4 + l4);

#define MFMA_QUAD(AI, BJ)                                                      \
    __builtin_amdgcn_s_setprio(1);                                             \
    _Pragma("unroll")                                                          \
    for (int i = 0; i < 4; ++i)                                                \
        _Pragma("unroll")                                                      \
        for (int j = 0; j < 2; ++j)                                            \
            _Pragma("unroll")                                                  \
            for (int ks = 0; ks < 2; ++ks)                                     \
                acc[(AI) + i][(BJ) + j] =                                      \
                    __builtin_amdgcn_mfma_f32_16x16x32_bf16(                   \
                        af[i][ks], bfr[j][ks], acc[(AI) + i][(BJ) + j], 0, 0, 0); \
    __builtin_amdgcn_s_setprio(0);

__global__ __launch_bounds__(512, 2) void gemm256_8phase_kernel(
    const bf16* __restrict__ A,     // (M, K) bf16
    const bf16* __restrict__ B,     // (N, K) bf16
    const float* __restrict__ bias, // (N,)
    float* __restrict__ out)        // (M, N) fp32
{
    __shared__ __align__(16) bf16 as_[2][256 * BK];   // 64 KiB
    __shared__ __align__(16) bf16 bs_[2][256 * BK];   // 64 KiB

    const int t    = threadIdx.x;
    const int lane = t & 63;
    const int wave = t >> 6;          // 0..7
    const int wm   = wave >> 2;       // 0..1  (M half)
    const int wn   = wave & 3;        // 0..3  (N quarter)
    const int l15  = lane & 15;
    const int l4   = lane >> 4;       // 0..3
    const int srow = lane >> 3;       // staging row within 8-row wave issue
    const int sun  = lane & 7;        // staging 16B unit

    // XCD-aware chunked swizzle (nwg = 16 * M/256, always a multiple of 8)
    const int nwg = (int)gridDim.x;
    const int cpx = nwg >> 3;
    const int wg  = ((int)blockIdx.x & 7) * cpx + ((int)blockIdx.x >> 3);
    const int n0  = (wg & 15) * 256;   // OUT_F/256 == 16
    const int m0  = (wg >> 4) * 256;

    floatx4 acc[8][4];
#pragma unroll
    for (int f = 0; f < 8; ++f)
#pragma unroll
        for (int g = 0; g < 4; ++g) acc[f][g] = (floatx4){0.f, 0.f, 0.f, 0.f};

    // ---- prologue: tile0 full (8 loads) + tile1 A-q0,q2 (2 loads) ----
#pragma unroll
    for (int q = 0; q < 4; ++q) STAGE(A, &as_[0][0], q, m0, 0);
#pragma unroll
    for (int q = 0; q < 4; ++q) STAGE(B, &bs_[0][0], q, n0, 0);
    STAGE(A, &as_[1][0], 0, m0, 1);
    STAGE(A, &as_[1][0], 2, m0, 1);
    asm volatile("s_waitcnt vmcnt(2)" ::: "memory");  // tile0 landed
    SBAR();

    bf16x8 af[4][2], bfr[2][2];

    for (int kt = 0; kt < NTILES; ++kt) {
        bf16* const At = &as_[kt & 1][0];
        bf16* const Bt = &bs_[kt & 1][0];
        bf16* const An = &as_[(kt & 1) ^ 1][0];
        bf16* const Bn = &bs_[(kt & 1) ^ 1][0];
        const int s1 = (kt + 1 < NTILES);
        const int s2 = (kt + 2 < NTILES);

        // ---- Phase 0: quadrant (ms=0, ns=0) ----
        LOAD_A(At, 0);
        LOAD_B(Bt, 0);
        if (s1) { STAGE(B, Bn, 0, n0, kt + 1); STAGE(B, Bn, 1, n0, kt + 1); }
        SBAR(); WAIT_LGKM0;
        MFMA_QUAD(0, 0);
        SBAR();

        // ---- Phase 1: (ms=0, ns=1) — reuses af ----
        LOAD_B(Bt, 1);
        if (s1) { STAGE(B, Bn, 2, n0, kt + 1); STAGE(B, Bn, 3, n0, kt + 1); }
        SBAR(); WAIT_LGKM0;
        MFMA_QUAD(0, 2);
        // counted wait: guarantees A-q1,q3 of tile kt (issued at kt-1 P2).
        // Steady state: 8 outstanding -> vmcnt(6) forces exactly those 2.
        // Tail (s1 false): only <=4 outstanding -> need vmcnt(0).
        if (s1) { asm volatile("s_waitcnt vmcnt(6)" ::: "memory"); }
        else    { asm volatile("s_waitcnt vmcnt(0)" ::: "memory"); }
        SBAR();

        // ---- Phase 2: (ms=1, ns=0) ----
        LOAD_A(At, 1);
        LOAD_B(Bt, 0);
        if (s1) { STAGE(A, An, 1, m0, kt + 1); STAGE(A, An, 3, m0, kt + 1); }
        SBAR(); WAIT_LGKM0;
        MFMA_QUAD(4, 0);
        SBAR();

        // ---- Phase 3: (ms=1, ns=1) — reuses af ----
        // A-q0/q2 of tile kt+2 go into the CURRENT A buffer: those regions
        // were last read at P0 (af held in regs since), 3 barriers ago. Safe.
        LOAD_B(Bt, 1);
        if (s2) { STAGE(A, At, 0, m0, kt + 2); STAGE(A, At, 2, m0, kt + 2); }
        SBAR(); WAIT_LGKM0;
        MFMA_QUAD(4, 2);
        // boundary wait: tile kt+1's B (kt P0/P1) + A-q0,q2 (kt-1 P3) landed.
        // Steady state: 10 outstanding -> vmcnt(4) leaves [kt P2, kt P3].
        // Tail (s2 false, kt = NTILES-2): only 6 outstanding -> vmcnt(2)
        // forces P0+P1 B stages of the last tile; leaves kt P2's A pair.
        if (s2) { asm volatile("s_waitcnt vmcnt(4)" ::: "memory"); }
        else    { asm volatile("s_waitcnt vmcnt(2)" ::: "memory"); }
        SBAR();
    }

    // epilogue: C/D layout col=lane&15, row=(lane>>4)*4+reg
#pragma unroll
    for (int g = 0; g < 4; ++g) {
        const int col = n0 + wn * 64 + g * 16 + l15;
        const float bv = bias[col];
#pragma unroll
        for (int f = 0; f < 8; ++f) {
            const int row = m0 + wm * 128 + f * 16 + l4 * 4;
#pragma unroll
            for (int r = 0; r < 4; ++r)
                out[(size_t)(row + r) * OUT_F + col] = acc[f][g][r] + bv;
        }
    }
}

// ---------------------------------------------------------------------------
// Fallback fused kernel (only if ws too small)
// ---------------------------------------------------------------------------
#define SA 72
#define SB 72
__global__ __launch_bounds__(256) void hqq_gemm_fused_kernel(
    const float* __restrict__ x, const int* __restrict__ Wp,
    const float* __restrict__ scale, const float* __restrict__ zero,
    const float* __restrict__ bias, float* __restrict__ out)
{
    __shared__ __align__(16) bf16 asmem[128 * SA];
    __shared__ __align__(16) bf16 bsmem[128 * SB];
    const int t = threadIdx.x, lane = t & 63, wave = t >> 6;
    const int lane16 = lane & 15, kq = lane >> 4;
    const int wm = wave >> 1, wn = wave & 1;
    const int n0 = blockIdx.x * 128, m0 = blockIdx.y * 128;
    floatx4 acc[4][4];
#pragma unroll
    for (int i = 0; i < 4; ++i)
#pragma unroll
        for (int j = 0; j < 4; ++j) acc[i][j] = (floatx4){0.f, 0.f, 0.f, 0.f};
    const int a_col4 = t & 15, a_row0 = t >> 4;
    const int b_nl = t >> 1, b_half = t & 1;
    for (int kt = 0; kt < IN_F / 64; ++kt) {
        const float* xp = x + (size_t)(m0 + a_row0) * IN_F + kt * 64 + a_col4 * 4;
#pragma unroll
        for (int p = 0; p < 8; ++p) {
            float4 v = *(const float4*)(xp + (size_t)(p * 16) * IN_F);
            bf16x4 b = { (bf16)v.x, (bf16)v.y, (bf16)v.z, (bf16)v.w };
            *(bf16x4*)&asmem[(a_row0 + p * 16) * SA + a_col4 * 4] = b;
        }
        {
            const int4 v = *(const int4*)(Wp + (size_t)(n0 + b_nl) * (IN_F / 8)
                                          + kt * 8 + b_half * 4);
            const int g = (n0 + b_nl) * (IN_F / 64) + kt;
            const float sc = scale[g], zp = zero[g];
            const bf16 hi = (bf16)((1.0f - zp) * sc), lo = (bf16)(0.0f - zp * sc);
            const int vals[4] = {v.x, v.y, v.z, v.w};
#pragma unroll
            for (int e = 0; e < 4; ++e) {
                bf16x8 w;
#pragma unroll
                for (int j = 0; j < 8; ++j) w[j] = ((vals[e] >> j) & 1) ? hi : lo;
                *(bf16x8*)&bsmem[b_nl * SB + b_half * 32 + e * 8] = w;
            }
        }
        __syncthreads();
#pragma unroll
        for (int ks = 0; ks < 2; ++ks) {
            bf16x8 af[4], bfr[4];
#pragma unroll
            for (int i = 0; i < 4; ++i)
                af[i] = *(const bf16x8*)&asmem[(wm * 64 + i * 16 + lane16) * SA + ks * 32 + kq * 8];
#pragma unroll
            for (int j = 0; j < 4; ++j)
                bfr[j] = *(const bf16x8*)&bsmem[(wn * 64 + j * 16 + lane16) * SB + ks * 32 + kq * 8];
#pragma unroll
            for (int i = 0; i < 4; ++i)
#pragma unroll
                for (int j = 0; j < 4; ++j)
                    acc[i][j] = __builtin_amdgcn_mfma_f32_16x16x32_bf16(af[i], bfr[j], acc[i][j], 0, 0, 0);
        }
        __syncthreads();
    }
#pragma unroll
    for (int j = 0; j < 4; ++j) {
        const int col = n0 + wn * 64 + j * 16 + lane16;
        const float bv = bias[col];
#pragma unroll
        for (int i = 0; i < 4; ++i) {
            const int row = m0 + wm * 64 + i * 16 + kq * 4;
#pragma unroll
            for (int r = 0; r < 4; ++r)
                out[(size_t)(row + r) * OUT_F + col] = acc[i][j][r] + bv;
        }
    }
}

// ---------------------------------------------------------------------------
extern "C" void kernel_launch(void* const* d_in, const int* in_sizes, int n_in,
                              void* d_out, int out_size, void* d_ws, size_t ws_size,
                              hipStream_t stream) {
    const float* x     = (const float*)d_in[0];
    const int*   Wp    = (const int*)d_in[1];
    const float* scale = (const float*)d_in[2];
    const float* zero  = (const float*)d_in[3];
    const float* bias  = (const float*)d_in[4];
    float*       out   = (float*)d_out;

    const int M = in_sizes[0] / IN_F;   // 8192
    const size_t need = (size_t)M * IN_F * 2 + (size_t)OUT_F * IN_F * 2;  // 96 MB

    if (ws_size >= need && (M % 256) == 0) {
        bf16* xb = (bf16*)d_ws;
        bf16* Wb = (bf16*)((char*)d_ws + (size_t)M * IN_F * 2);

        const int nxb = (M * IN_F / 8) / 256;        // x-convert blocks (8 floats/thr)
        const int nwb = (OUT_F * IN_F / 8) / 256;    // dequant blocks
        prep_kernel<<<nxb + nwb, 256, 0, stream>>>(x, xb, Wp, scale, zero, Wb, nxb);

        gemm256_8phase_kernel<<<dim3((OUT_F / 256) * (M / 256)), 512, 0, stream>>>(
            xb, Wb, bias, out);
    } else {
        dim3 grid(OUT_F / 128, M / 128);
        hqq_gemm_fused_kernel<<<grid, 256, 0, stream>>>(x, Wp, scale, zero, bias, out);
    }
}

// Round 3
// 469.089 us; speedup vs baseline: 1.0821x; 1.0323x over previous
//
#include <hip/hip_runtime.h>
#include <hip/hip_bf16.h>

#define IN_F   4096
#define OUT_F  4096
#define BK     64
#define NTILES (IN_F / BK)   // 64

typedef __bf16 bf16;
typedef __attribute__((ext_vector_type(8)))  __bf16 bf16x8;
typedef __attribute__((ext_vector_type(4)))  __bf16 bf16x4;
typedef __attribute__((ext_vector_type(4)))  float  floatx4;

// ---------------------------------------------------------------------------
// Merged pre-pass: blocks [0, nxb) convert x fp32->bf16 (8 floats/thread,
// 32B loads + 16B stores); blocks [nxb, ...) unpack+dequant W to bf16 (N,K).
// ---------------------------------------------------------------------------
__global__ __launch_bounds__(256) void prep_kernel(
    const float* __restrict__ x,  bf16* __restrict__ xb,
    const int* __restrict__ Wp,   const float* __restrict__ scale,
    const float* __restrict__ zero, bf16* __restrict__ Wb, int nxb)
{
    if ((int)blockIdx.x < nxb) {
        const size_t i = (size_t)blockIdx.x * 256 + threadIdx.x;
        const float4 v0 = ((const float4*)x)[2 * i];
        const float4 v1 = ((const float4*)x)[2 * i + 1];
        bf16x8 b;
        b[0] = (bf16)v0.x; b[1] = (bf16)v0.y; b[2] = (bf16)v0.z; b[3] = (bf16)v0.w;
        b[4] = (bf16)v1.x; b[5] = (bf16)v1.y; b[6] = (bf16)v1.z; b[7] = (bf16)v1.w;
        ((bf16x8*)xb)[i] = b;
    } else {
        const int tid = (blockIdx.x - nxb) * 256 + threadIdx.x;  // one packed word
        const int n = tid >> 9;                  // / (IN_F/8)
        const int b = tid & 511;
        const int g = (n << 6) + (b >> 3);       // group = n*64 + k/64
        const float sc = scale[g];
        const float zp = zero[g];
        const bf16 hi = (bf16)((1.0f - zp) * sc);
        const bf16 lo = (bf16)((0.0f - zp) * sc);
        const int v = Wp[tid];
        bf16x8 w;
#pragma unroll
        for (int j = 0; j < 8; ++j) w[j] = ((v >> j) & 1) ? hi : lo;
        *(bf16x8*)&Wb[(size_t)tid * 8] = w;
    }
}

// ---------------------------------------------------------------------------
// 256x256x64 8-phase counted-vmcnt GEMM (m201 template, plain HIP).
// Round-3 change: B fragments for BOTH N-halves held in registers across the
// K-tile (bf0, bf1) -> 24 ds_read_b128/lane/K-tile (384 B/lane) instead of 32
// (512 B/lane). LDS-read floor drops 1000->750 cy/K-tile/CU; MfmaUtil ceiling
// rises 61% -> ~82%. Stage schedule + vmcnt arithmetic unchanged from the
// verified round-2 kernel. P3 has no ds_reads -> its pre-MFMA barrier dropped
// (uniformly, so barrier counts stay aligned across waves).
// ---------------------------------------------------------------------------
__device__ __forceinline__ void gload_lds16(const void* g, void* l) {
    __builtin_amdgcn_global_load_lds(
        (const __attribute__((address_space(1))) unsigned int*)g,
        (__attribute__((address_space(3))) unsigned int*)l, 16, 0, 0);
}

#define CFENCE asm volatile("" ::: "memory")
#define SBAR() do { CFENCE; __builtin_amdgcn_s_barrier(); CFENCE; } while (0)
#define WAIT_LGKM0 asm volatile("s_waitcnt lgkmcnt(0)" ::: "memory")

// stage one 64-row quarter (q) of a (row0 + 256)x64 K-slab into LDS tile.
// wave w stages rows q*64 + w*8 .. +8; lane l: row += l>>3, stored unit l&7,
// global unit (l&7) ^ (row&7)  => LDS[r][s] = G[r][s ^ (r&7)].
#define STAGE(src, ldsTile, q, row0, kti) do {                                 \
    const int r_  = (q) * 64 + wave * 8 + srow;                                \
    const int gu_ = sun ^ (r_ & 7);                                            \
    gload_lds16((src) + (size_t)((row0) + r_) * IN_F + (kti) * BK + gu_ * 8,   \
                (ldsTile) + ((q) * 64 + wave * 8) * BK);                       \
} while (0)

// read a bf16x8 fragment: logical (row, 16B-unit u) -> stored unit u^(row&7)
#define LDFRAG(tile, row, u) \
    (*(const bf16x8*)((tile) + (row) * BK + (((u) ^ ((row) & 7)) << 3)))

#define LOAD_A(tile, MS)                                                       \
    _Pragma("unroll")                                                          \
    for (int i = 0; i < 4; ++i)                                                \
        _Pragma("unroll")                                                      \
        for (int ks = 0; ks < 2; ++ks)                                         \
            af[i][ks] = LDFRAG((tile), wm * 128 + (MS) * 64 + i * 16 + l15,    \
                               ks * 4 + l4);

#define LOAD_B_TO(dst, tile, NS)                                               \
    _Pragma("unroll")                                                          \
    for (int j = 0; j < 2; ++j)                                                \
        _Pragma("unroll")                                                      \
        for (int ks = 0; ks < 2; ++ks)                                         \
            dst[j][ks] = LDFRAG((tile), wn * 64 + (NS) * 32 + j * 16 + l15,    \
                                ks * 4 + l4);

#define MFMA_QUAD(AI, BJ, BFR)                                                 \
    __builtin_amdgcn_s_setprio(1);                                             \
    _Pragma("unroll")                                                          \
    for (int i = 0; i < 4; ++i)                                                \
        _Pragma("unroll")                                                      \
        for (int j = 0; j < 2; ++j)                                            \
            _Pragma("unroll")                                                  \
            for (int ks = 0; ks < 2; ++ks)                                     \
                acc[(AI) + i][(BJ) + j] =                                      \
                    __builtin_amdgcn_mfma_f32_16x16x32_bf16(                   \
                        af[i][ks], BFR[j][ks], acc[(AI) + i][(BJ) + j], 0, 0, 0); \
    __builtin_amdgcn_s_setprio(0);

__global__ __launch_bounds__(512, 2) void gemm256_8phase_kernel(
    const bf16* __restrict__ A,     // (M, K) bf16
    const bf16* __restrict__ B,     // (N, K) bf16
    const float* __restrict__ bias, // (N,)
    float* __restrict__ out)        // (M, N) fp32
{
    __shared__ __align__(16) bf16 as_[2][256 * BK];   // 64 KiB
    __shared__ __align__(16) bf16 bs_[2][256 * BK];   // 64 KiB

    const int t    = threadIdx.x;
    const int lane = t & 63;
    const int wave = t >> 6;          // 0..7
    const int wm   = wave >> 2;       // 0..1  (M half)
    const int wn   = wave & 3;        // 0..3  (N quarter)
    const int l15  = lane & 15;
    const int l4   = lane >> 4;       // 0..3
    const int srow = lane >> 3;       // staging row within 8-row wave issue
    const int sun  = lane & 7;        // staging 16B unit

    // XCD-aware chunked swizzle (nwg = 16 * M/256, always a multiple of 8)
    const int nwg = (int)gridDim.x;
    const int cpx = nwg >> 3;
    const int wg  = ((int)blockIdx.x & 7) * cpx + ((int)blockIdx.x >> 3);
    const int n0  = (wg & 15) * 256;   // OUT_F/256 == 16
    const int m0  = (wg >> 4) * 256;

    floatx4 acc[8][4];
#pragma unroll
    for (int f = 0; f < 8; ++f)
#pragma unroll
        for (int g = 0; g < 4; ++g) acc[f][g] = (floatx4){0.f, 0.f, 0.f, 0.f};

    // ---- prologue: tile0 full (8 loads) + tile1 A-q0,q2 (2 loads) ----
#pragma unroll
    for (int q = 0; q < 4; ++q) STAGE(A, &as_[0][0], q, m0, 0);
#pragma unroll
    for (int q = 0; q < 4; ++q) STAGE(B, &bs_[0][0], q, n0, 0);
    STAGE(A, &as_[1][0], 0, m0, 1);
    STAGE(A, &as_[1][0], 2, m0, 1);
    asm volatile("s_waitcnt vmcnt(2)" ::: "memory");  // tile0 landed
    SBAR();

    bf16x8 af[4][2], bf0[2][2], bf1[2][2];

    for (int kt = 0; kt < NTILES; ++kt) {
        bf16* const At = &as_[kt & 1][0];
        bf16* const Bt = &bs_[kt & 1][0];
        bf16* const An = &as_[(kt & 1) ^ 1][0];
        bf16* const Bn = &bs_[(kt & 1) ^ 1][0];
        const int s1 = (kt + 1 < NTILES);
        const int s2 = (kt + 2 < NTILES);

        // ---- Phase 0: quadrant (ms=0, ns=0) ----
        LOAD_A(At, 0);
        LOAD_B_TO(bf0, Bt, 0);
        if (s1) { STAGE(B, Bn, 0, n0, kt + 1); STAGE(B, Bn, 1, n0, kt + 1); }
        SBAR(); WAIT_LGKM0;
        MFMA_QUAD(0, 0, bf0);
        SBAR();

        // ---- Phase 1: (ms=0, ns=1) — reuses af ----
        LOAD_B_TO(bf1, Bt, 1);
        if (s1) { STAGE(B, Bn, 2, n0, kt + 1); STAGE(B, Bn, 3, n0, kt + 1); }
        SBAR(); WAIT_LGKM0;
        MFMA_QUAD(0, 2, bf1);
        // counted wait: guarantees A-q1,q3 of tile kt (issued at kt-1 P2).
        // Steady state: 8 outstanding -> vmcnt(6) forces exactly those 2.
        // Tail (s1 false): fewer outstanding -> need vmcnt(0).
        if (s1) { asm volatile("s_waitcnt vmcnt(6)" ::: "memory"); }
        else    { asm volatile("s_waitcnt vmcnt(0)" ::: "memory"); }
        SBAR();

        // ---- Phase 2: (ms=1, ns=0) — reuses bf0 ----
        LOAD_A(At, 1);
        if (s1) { STAGE(A, An, 1, m0, kt + 1); STAGE(A, An, 3, m0, kt + 1); }
        SBAR(); WAIT_LGKM0;
        MFMA_QUAD(4, 0, bf0);
        SBAR();

        // ---- Phase 3: (ms=1, ns=1) — reuses af and bf1, no ds_reads ----
        // A-q0/q2 of tile kt+2 go into the CURRENT A buffer: those regions
        // were last read at P0 (af held in regs since), 3 barriers ago. Safe.
        if (s2) { STAGE(A, At, 0, m0, kt + 2); STAGE(A, At, 2, m0, kt + 2); }
        MFMA_QUAD(4, 2, bf1);
        // boundary wait: tile kt+1's B (kt P0/P1) + A-q0,q2 (kt-1 P3) landed.
        // Steady state: 10 outstanding -> vmcnt(4) leaves [kt P2, kt P3].
        // Tail (s2 false, kt = NTILES-2): vmcnt(2) forces last tile's B
        // stages; leaves kt P2's A pair (forced by P1-end vmcnt(0) next it).
        if (s2) { asm volatile("s_waitcnt vmcnt(4)" ::: "memory"); }
        else    { asm volatile("s_waitcnt vmcnt(2)" ::: "memory"); }
        SBAR();
    }

    // epilogue: C/D layout col=lane&15, row=(lane>>4)*4+reg
#pragma unroll
    for (int g = 0; g < 4; ++g) {
        const int col = n0 + wn * 64 + g * 16 + l15;
        const float bv = bias[col];
#pragma unroll
        for (int f = 0; f < 8; ++f) {
            const int row = m0 + wm * 128 + f * 16 + l4 * 4;
#pragma unroll
            for (int r = 0; r < 4; ++r)
                out[(size_t)(row + r) * OUT_F + col] = acc[f][g][r] + bv;
        }
    }
}

// ---------------------------------------------------------------------------
// Fallback fused kernel (only if ws too small)
// ---------------------------------------------------------------------------
#define SA 72
#define SB 72
__global__ __launch_bounds__(256) void hqq_gemm_fused_kernel(
    const float* __restrict__ x, const int* __restrict__ Wp,
    const float* __restrict__ scale, const float* __restrict__ zero,
    const float* __restrict__ bias, float* __restrict__ out)
{
    __shared__ __align__(16) bf16 asmem[128 * SA];
    __shared__ __align__(16) bf16 bsmem[128 * SB];
    const int t = threadIdx.x, lane = t & 63, wave = t >> 6;
    const int lane16 = lane & 15, kq = lane >> 4;
    const int wm = wave >> 1, wn = wave & 1;
    const int n0 = blockIdx.x * 128, m0 = blockIdx.y * 128;
    floatx4 acc[4][4];
#pragma unroll
    for (int i = 0; i < 4; ++i)
#pragma unroll
        for (int j = 0; j < 4; ++j) acc[i][j] = (floatx4){0.f, 0.f, 0.f, 0.f};
    const int a_col4 = t & 15, a_row0 = t >> 4;
    const int b_nl = t >> 1, b_half = t & 1;
    for (int kt = 0; kt < IN_F / 64; ++kt) {
        const float* xp = x + (size_t)(m0 + a_row0) * IN_F + kt * 64 + a_col4 * 4;
#pragma unroll
        for (int p = 0; p < 8; ++p) {
            float4 v = *(const float4*)(xp + (size_t)(p * 16) * IN_F);
            bf16x4 b = { (bf16)v.x, (bf16)v.y, (bf16)v.z, (bf16)v.w };
            *(bf16x4*)&asmem[(a_row0 + p * 16) * SA + a_col4 * 4] = b;
        }
        {
            const int4 v = *(const int4*)(Wp + (size_t)(n0 + b_nl) * (IN_F / 8)
                                          + kt * 8 + b_half * 4);
            const int g = (n0 + b_nl) * (IN_F / 64) + kt;
            const float sc = scale[g], zp = zero[g];
            const bf16 hi = (bf16)((1.0f - zp) * sc), lo = (bf16)(0.0f - zp * sc);
            const int vals[4] = {v.x, v.y, v.z, v.w};
#pragma unroll
            for (int e = 0; e < 4; ++e) {
                bf16x8 w;
#pragma unroll
                for (int j = 0; j < 8; ++j) w[j] = ((vals[e] >> j) & 1) ? hi : lo;
                *(bf16x8*)&bsmem[b_nl * SB + b_half * 32 + e * 8] = w;
            }
        }
        __syncthreads();
#pragma unroll
        for (int ks = 0; ks < 2; ++ks) {
            bf16x8 af[4], bfr[4];
#pragma unroll
            for (int i = 0; i < 4; ++i)
                af[i] = *(const bf16x8*)&asmem[(wm * 64 + i * 16 + lane16) * SA + ks * 32 + kq * 8];
#pragma unroll
            for (int j = 0; j < 4; ++j)
                bfr[j] = *(const bf16x8*)&bsmem[(wn * 64 + j * 16 + lane16) * SB + ks * 32 + kq * 8];
#pragma unroll
            for (int i = 0; i < 4; ++i)
#pragma unroll
                for (int j = 0; j < 4; ++j)
                    acc[i][j] = __builtin_amdgcn_mfma_f32_16x16x32_bf16(af[i], bfr[j], acc[i][j], 0, 0, 0);
        }
        __syncthreads();
    }
#pragma unroll
    for (int j = 0; j < 4; ++j) {
        const int col = n0 + wn * 64 + j * 16 + lane16;
        const float bv = bias[col];
#pragma unroll
        for (int i = 0; i < 4; ++i) {
            const int row = m0 + wm * 64 + i * 16 + kq * 4;
#pragma unroll
            for (int r = 0; r < 4; ++r)
                out[(size_t)(row + r) * OUT_F + col] = acc[i][j][r] + bv;
        }
    }
}

// ---------------------------------------------------------------------------
extern "C" void kernel_launch(void* const* d_in, const int* in_sizes, int n_in,
                              void* d_out, int out_size, void* d_ws, size_t ws_size,
                              hipStream_t stream) {
    const float* x     = (const float*)d_in[0];
    const int*   Wp    = (const int*)d_in[1];
    const float* scale = (const float*)d_in[2];
    const float* zero  = (const float*)d_in[3];
    const float* bias  = (const float*)d_in[4];
    float*       out   = (float*)d_out;

    const int M = in_sizes[0] / IN_F;   // 8192
    const size_t need = (size_t)M * IN_F * 2 + (size_t)OUT_F * IN_F * 2;  // 96 MB

    if (ws_size >= need && (M % 256) == 0) {
        bf16* xb = (bf16*)d_ws;
        bf16* Wb = (bf16*)((char*)d_ws + (size_t)M * IN_F * 2);

        const int nxb = (M * IN_F / 8) / 256;        // x-convert blocks (8 floats/thr)
        const int nwb = (OUT_F * IN_F / 8) / 256;    // dequant blocks
        prep_kernel<<<nxb + nwb, 256, 0, stream>>>(x, xb, Wp, scale, zero, Wb, nxb);

        gemm256_8phase_kernel<<<dim3((OUT_F / 256) * (M / 256)), 512, 0, stream>>>(
            xb, Wb, bias, out);
    } else {
        dim3 grid(OUT_F / 128, M / 128);
        hqq_gemm_fused_kernel<<<grid, 256, 0, stream>>>(x, Wp, scale, zero, bias, out);
    }
}